// Round 1
// baseline (1315.643 us; speedup 1.0000x reference)
//
#include <hip/hip_runtime.h>
#include <math.h>

#define BATCH 262144
#define NUM_CLASSES 1000
// ALPHA=1.0, GAMMA=2.0, K=0.5, T=3.0 baked in below.

// One wave (64 lanes) per row. 1000 floats = 250 float4; lane loads float4
// indices lane, lane+64, lane+128, lane+192 (last chunk partial: 58 lanes).
__global__ __launch_bounds__(256) void dbfl_main(
    const float* __restrict__ output,   // [BATCH, NUM_CLASSES]
    const int* __restrict__ target,     // [BATCH]
    const float* __restrict__ wt,       // [NUM_CLASSES, NUM_CLASSES]
    double* __restrict__ acc)           // acc[0]=loss1, acc[1]=loss2
{
    const int lane = threadIdx.x & 63;
    const int wib  = threadIdx.x >> 6;                       // wave in block
    const int wpb  = blockDim.x >> 6;                        // waves per block
    const long long gwave  = (long long)blockIdx.x * wpb + wib;
    const long long nwaves = (long long)gridDim.x * wpb;

    float acc1 = 0.f, acc2 = 0.f;

    for (long long row = gwave; row < BATCH; row += nwaves) {
        const float* rp = output + row * (long long)NUM_CLASSES;
        const float4* rp4 = (const float4*)rp;               // 4000 % 16 == 0 -> aligned

        float4 v[4];
#pragma unroll
        for (int c = 0; c < 4; ++c) {
            int f = lane + 64 * c;
            if (f < NUM_CLASSES / 4) {
                v[c] = rp4[f];
            } else {
                v[c] = make_float4(-INFINITY, -INFINITY, -INFINITY, -INFINITY);
            }
        }

        // per-lane max + argmax (first-occurrence tie-break: smaller col wins)
        float bm = -INFINITY; int bi = NUM_CLASSES;
#pragma unroll
        for (int c = 0; c < 4; ++c) {
            const int base = (lane + 64 * c) * 4;
            const float vv[4] = {v[c].x, v[c].y, v[c].z, v[c].w};
#pragma unroll
            for (int j = 0; j < 4; ++j) {
                const float x = vv[j]; const int col = base + j;
                if (x > bm || (x == bm && col < bi)) { bm = x; bi = col; }
            }
        }

        // wave butterfly reduce (max, argmax)
        float wm = bm; int wi = bi;
#pragma unroll
        for (int off = 32; off > 0; off >>= 1) {
            float om = __shfl_xor(wm, off, 64);
            int   oi = __shfl_xor(wi, off, 64);
            if (om > wm || (om == wm && oi < wi)) { wm = om; wi = oi; }
        }

        // per-lane sum of exp(x - wm); -inf lanes contribute exp(-inf)=0
        float s = 0.f;
#pragma unroll
        for (int c = 0; c < 4; ++c) {
            s += __expf(v[c].x - wm);
            s += __expf(v[c].y - wm);
            s += __expf(v[c].z - wm);
            s += __expf(v[c].w - wm);
        }
#pragma unroll
        for (int off = 32; off > 0; off >>= 1)
            s += __shfl_xor(s, off, 64);

        if (lane == 0) {
            const int t  = target[row];
            const float xt = rp[t];                           // L1 hit (row just read)
            const float ce = wm + __logf(s) - xt;             // lse - x_t
            const float pt = __expf(-ce);
            const float om_pt = 1.f - pt;
            const float fl = om_pt * om_pt * ce;              // alpha=1, gamma=2
            const float w  = wt[t * NUM_CLASSES + wi];
            if (w != 0.f) acc1 += fl * w;                     // mask <=> weight nonzero
            else          acc2 += fl;
        }
    }

    __shared__ float sh1[8], sh2[8];
    if (lane == 0) { sh1[wib] = acc1; sh2[wib] = acc2; }
    __syncthreads();
    if (threadIdx.x == 0) {
        float a = 0.f, b = 0.f;
        for (int i = 0; i < wpb; ++i) { a += sh1[i]; b += sh2[i]; }
        unsafeAtomicAdd(&acc[0], (double)a);                  // HW global_atomic_add_f64
        unsafeAtomicAdd(&acc[1], (double)b);
    }
}

__global__ void dbfl_final(const double* __restrict__ acc, float* __restrict__ out)
{
    const double loss1 = acc[0];
    const double loss2 = acc[1];
    const double b  = (double)BATCH;
    const double l1 = loss1 / b;
    const double l2 = loss2 / b;
    const double w2 = 1.0 / (1.0 + exp(-0.5 * (l1 - 3.0)));   // sigmoid(K*(l1-T))
    const double total = (loss1 > 0.0) ? (l1 + w2 * l2) : l2;
    out[0] = (float)total;
}

extern "C" void kernel_launch(void* const* d_in, const int* in_sizes, int n_in,
                              void* d_out, int out_size, void* d_ws, size_t ws_size,
                              hipStream_t stream)
{
    const float* output = (const float*)d_in[0];
    const int*   target = (const int*)d_in[1];
    const float* wt     = (const float*)d_in[2];
    // d_in[3] (in_dict bool mask) intentionally unused: mask <=> wt != 0.

    double* acc = (double*)d_ws;
    hipMemsetAsync(d_ws, 0, 2 * sizeof(double), stream);      // ws is poisoned 0xAA

    const int block = 256;                                     // 4 waves/block
    const int grid  = 2048;                                    // 8192 waves, 32 rows each
    dbfl_main<<<grid, block, 0, stream>>>(output, target, wt, acc);
    dbfl_final<<<1, 1, 0, stream>>>(acc, (float*)d_out);
}